// Round 8
// baseline (194.979 us; speedup 1.0000x reference)
//
#include <hip/hip_runtime.h>

// A8W8 GEMM, fp16-saturating output. C = (a_i8 @ b_i8^T) * arow * acol.
// Pass 1: pack int32 -> int8. Pass 2: 256x256 tile, BKB=64, 8 waves,
// 4-slot circular LDS, ONE barrier + ONE counted vmcnt per K-step.
// Register-lean read-ahead: af[8] rotates IN-PLACE (tile j+1 frags read
// right after each m-pair's MFMA cluster), bf[4] ping-pongs. ~232 regs,
// no spill. R3's verified staging swizzle (0 bank conflicts).

constexpr int MD = 4096, ND = 4096, KD = 4096;
constexpr int BM = 256, BN = 256, BKB = 64;  // K-step bytes (= 64 i8 = MFMA K)
constexpr int NT = KD / BKB;                 // 64 K-steps
constexpr int TB = BM * BKB;                 // 16 KiB per matrix per slot

using i32x4 = __attribute__((ext_vector_type(4))) int;

#define VMCNT(n) asm volatile("s_waitcnt vmcnt(" #n ")" ::: "memory")
#define BAR() __builtin_amdgcn_s_barrier()

// ---------------- pack: int32 (one value per elem) -> int8 ----------------
__global__ __launch_bounds__(256) void pack_i8(const int* __restrict__ in,
                                               char* __restrict__ out) {
  const size_t t = (size_t)blockIdx.x * 256 + threadIdx.x;
  const int4* p = (const int4*)in + t * 4;
  int4 v0 = p[0], v1 = p[1], v2 = p[2], v3 = p[3];
  int4 o;
  o.x = v0.x | (v0.y << 8) | (v0.z << 16) | (v0.w << 24);
  o.y = v1.x | (v1.y << 8) | (v1.z << 16) | (v1.w << 24);
  o.z = v2.x | (v2.y << 8) | (v2.z << 16) | (v2.w << 24);
  o.w = v3.x | (v3.y << 8) | (v3.z << 16) | (v3.w << 24);
  ((int4*)out)[t] = o;
}

// ---------------- GEMM ----------------------------------------------------
__device__ inline void load16_lds(const char* g, char* l) {
  __builtin_amdgcn_global_load_lds(
      (const __attribute__((address_space(1))) void*)g,
      (__attribute__((address_space(3))) void*)l, 16, 0, 0);
}

// reference fp16 cast, saturating (all values >= 0; |inf-finite|=inf passes)
__device__ inline float f16_sat(float v) {
  v = fminf(v, 65504.0f);
  return (float)(_Float16)v;
}

__global__ __launch_bounds__(512, 2) void gemm_i8w8(
    const char* __restrict__ A, const char* __restrict__ B,
    const float* __restrict__ arow, const float* __restrict__ acol,
    float* __restrict__ out) {
  __shared__ char sA[4][TB];  // 64 KiB
  __shared__ char sB[4][TB];  // 64 KiB

  const int tid = threadIdx.x;
  const int wv = tid >> 6;
  const int lane = tid & 63;

  // XCD-aware bijective swizzle (nwg = 256, divisible by 8)
  const int bid = blockIdx.x;
  const int wg = (bid & 7) * 32 + (bid >> 3);
  const int brow = wg >> 4;
  const int bcol = wg & 15;

  // 2(M) x 4(N) wave grid; per-wave output 128 x 64
  const int wrow = (wv >> 2) * 128;
  const int wcol = (wv & 3) * 64;

  i32x4 acc[8][4] = {};

  // ---- staging (R3-verified): per K-step each matrix = 1024 chunks of
  // 16B; thread owns chunks c0=tid, c1=tid+512. LDS dest LINEAR (gload:
  // wave base + lane*16). Source slot pre-swizzled (rule 21):
  // LDS[row][s] = G[row][s ^ ((row>>1)&3)], row = c>>2, s = c&3.
  const int c0 = tid, c1 = tid + 512;
  const int sg0 = ((c0 & 3) ^ ((c0 >> 3) & 3)) * 16;
  const int sg1 = ((c1 & 3) ^ ((c1 >> 3) & 3)) * 16;
  const char* aSrc0 = A + (size_t)(brow * BM + (c0 >> 2)) * KD + sg0;
  const char* aSrc1 = A + (size_t)(brow * BM + (c1 >> 2)) * KD + sg1;
  const char* bSrc0 = B + (size_t)(bcol * BN + (c0 >> 2)) * KD + sg0;
  const char* bSrc1 = B + (size_t)(bcol * BN + (c1 >> 2)) * KD + sg1;
  const int ldsOff0 = wv * 1024;         // chunks [wv*64, wv*64+64)
  const int ldsOff1 = 8192 + wv * 1024;  // chunks [512+wv*64, ...)

  auto issue_tile = [&](int s, int t) {  // 4 gloads, slot s <- K-step t
    const size_t ko = (size_t)t * BKB;
    load16_lds(aSrc0 + ko, sA[s] + ldsOff0);
    load16_lds(aSrc1 + ko, sA[s] + ldsOff1);
    load16_lds(bSrc0 + ko, sB[s] + ldsOff0);
    load16_lds(bSrc1 + ko, sB[s] + ldsOff1);
  };

  // ---- fragment reads (R3-verified, 0 bank conflicts): lane l -> row
  // base+(l&15), G-slot (l>>4); LDS slot = (l>>4) ^ ((row>>1)&3).
  const int r = lane & 15;
  const int sl = ((lane >> 4) ^ ((r >> 1) & 3)) * 16;
  const int aBase = (wrow + r) * BKB + sl;  // + m*1024 per frag
  const int bBase = (wcol + r) * BKB + sl;  // + n*1024 per frag

  i32x4 af[8], bfA[4], bfB[4];

  // ---- one K-step, ONE barrier, ONE counted vmcnt.
  // Entering iter j: af = A(tile j), bfC = B(tile j) (read in iter j-1);
  // tile j+1 landed & barrier-published; tile j+2 in flight.
  auto body = [&](int j, int sc, int sn, int ss, i32x4(&bfC)[4],
                  i32x4(&bfN)[4]) {
    if (j + 3 < NT) issue_tile(ss, j + 3);  // slot ss: last read iter j-2
    const bool rd = (j + 1) < NT;
    const char* pan = sA[sn] + aBase;
    const char* pbn = sB[sn] + bBase;
    if (rd) {
#pragma unroll
      for (int n = 0; n < 4; ++n)
        bfN[n] = *(const i32x4*)(pbn + n * 1024);
    }
#pragma unroll
    for (int mp = 0; mp < 4; ++mp) {  // m-pair clusters, af rotates in-place
      __builtin_amdgcn_s_setprio(1);
#pragma unroll
      for (int m = 2 * mp; m < 2 * mp + 2; ++m)
#pragma unroll
        for (int n = 0; n < 4; ++n)
          acc[m][n] = __builtin_amdgcn_mfma_i32_16x16x64_i8(af[m], bfC[n],
                                                            acc[m][n], 0, 0, 0);
      __builtin_amdgcn_s_setprio(0);
      if (rd) {  // WAR on af[2mp..2mp+1]: their MFMAs already issued
        af[2 * mp] = *(const i32x4*)(pan + (2 * mp) * 1024);
        af[2 * mp + 1] = *(const i32x4*)(pan + (2 * mp + 1) * 1024);
      }
    }
    if (j <= NT - 4) {
      VMCNT(4);  // retire tile j+2 (read next iter); keep tile j+3 in flight
    } else {
      VMCNT(0);  // tail drain
    }
    BAR();
  };

  // ---- prologue: 3 tiles in flight; retire tiles 0 AND 1 (tile 1 is
  // read mid-iter-0, so it must be published by this vmcnt+BAR pair);
  // then pre-read af/bf of tile 0.
  issue_tile(0, 0);
  issue_tile(1, 1);
  issue_tile(2, 2);
  VMCNT(4);  // tiles 0,1 landed; tile 2 in flight
  BAR();
  {
    const char* pa0 = sA[0] + aBase;
    const char* pb0 = sB[0] + bBase;
#pragma unroll
    for (int m = 0; m < 8; ++m) af[m] = *(const i32x4*)(pa0 + m * 1024);
#pragma unroll
    for (int n = 0; n < 4; ++n) bfA[n] = *(const i32x4*)(pb0 + n * 1024);
  }

  for (int j4 = 0; j4 < NT; j4 += 4) {  // slots 0,1,2,3; bf ping-pong
    body(j4 + 0, 0, 1, 3, bfA, bfB);
    body(j4 + 1, 1, 2, 0, bfB, bfA);
    body(j4 + 2, 2, 3, 1, bfA, bfB);
    body(j4 + 3, 3, 0, 2, bfB, bfA);
  }

  // ---- epilogue: C/D map col=lane&15, row=(lane>>4)*4+reg (16x16 shapes)
  const int orow0 = brow * BM + wrow + ((lane >> 4) << 2);
  const int ocol0 = bcol * BN + wcol + (lane & 15);
#pragma unroll
  for (int m = 0; m < 8; ++m) {
    const int rb = orow0 + m * 16;
    const float ar0 = arow[rb + 0], ar1 = arow[rb + 1];
    const float ar2 = arow[rb + 2], ar3 = arow[rb + 3];
#pragma unroll
    for (int n = 0; n < 4; ++n) {
      const int col = ocol0 + n * 16;
      const float ac = acol[col];
      out[(size_t)(rb + 0) * ND + col] = f16_sat((float)acc[m][n][0] * (ar0 * ac));
      out[(size_t)(rb + 1) * ND + col] = f16_sat((float)acc[m][n][1] * (ar1 * ac));
      out[(size_t)(rb + 2) * ND + col] = f16_sat((float)acc[m][n][2] * (ar2 * ac));
      out[(size_t)(rb + 3) * ND + col] = f16_sat((float)acc[m][n][3] * (ar3 * ac));
    }
  }
}

extern "C" void kernel_launch(void* const* d_in, const int* in_sizes, int n_in,
                              void* d_out, int out_size, void* d_ws, size_t ws_size,
                              hipStream_t stream) {
  const int* a = (const int*)d_in[0];         // [M,K] int32 (int8 values)
  const int* b = (const int*)d_in[1];         // [N,K] int32 (int8 values)
  const float* arow = (const float*)d_in[2];  // [M,1]
  const float* acol = (const float*)d_in[3];  // [1,N]
  float* out = (float*)d_out;

  char* pa = (char*)d_ws;                    // 16 MiB packed A
  char* pb = pa + (size_t)MD * KD;           // 16 MiB packed B

  const int packBlocks = (int)(((size_t)MD * KD) / (16 * 256));  // 4096
  pack_i8<<<packBlocks, 256, 0, stream>>>(a, pa);
  pack_i8<<<packBlocks, 256, 0, stream>>>(b, pb);

  const int grid = (MD / BM) * (ND / BN);  // 256 blocks, 1 per CU
  gemm_i8w8<<<grid, 512, 0, stream>>>(pa, pb, arow, acol, out);
}

// Round 9
// 93.512 us; speedup vs baseline: 2.0851x; 2.0851x over previous
//
#include <hip/hip_runtime.h>

// A8W8 GEMM, fp16-saturating output. C = (a_i8 @ b_i8^T) * arow * acol.
// Pass 1: pack int32 -> int8. Pass 2: 256x256 tile, BKB=128, 8 waves,
// mfma_i32_32x32x32_i8, ks-sliced 4-phase pipeline with ONE barrier +
// ONE vmcnt(0) per K-tile (placed 2 phases after the stage issue, so the
// drain is cheap). U/V fragment ping-pong (48 regs) stays in budget.
// Both-sides XOR swizzle slot^=(row&7) (rule 21), sched_barrier fences.

constexpr int MD = 4096, ND = 4096, KD = 4096;
constexpr int BM = 256, BN = 256, BKB = 128;  // K-tile bytes (128 i8)
constexpr int NT = KD / BKB;                  // 32 K-tiles
constexpr int TB = BM * BKB;                  // 32 KiB per matrix per buffer

using i32x4 = __attribute__((ext_vector_type(4))) int;
using i32x16 = __attribute__((ext_vector_type(16))) int;

#define VMCNT(n) asm volatile("s_waitcnt vmcnt(" #n ")" ::: "memory")
#define BAR() __builtin_amdgcn_s_barrier()
#define SCHED_FENCE() __builtin_amdgcn_sched_barrier(0)

// ---------------- pack: int32 (one value per elem) -> int8 ----------------
__global__ __launch_bounds__(256) void pack_i8(const int* __restrict__ in,
                                               char* __restrict__ out) {
  const size_t t = (size_t)blockIdx.x * 256 + threadIdx.x;
  const int4* p = (const int4*)in + t * 4;
  int4 v0 = p[0], v1 = p[1], v2 = p[2], v3 = p[3];
  int4 o;
  o.x = v0.x | (v0.y << 8) | (v0.z << 16) | (v0.w << 24);
  o.y = v1.x | (v1.y << 8) | (v1.z << 16) | (v1.w << 24);
  o.z = v2.x | (v2.y << 8) | (v2.z << 16) | (v2.w << 24);
  o.w = v3.x | (v3.y << 8) | (v3.z << 16) | (v3.w << 24);
  ((int4*)out)[t] = o;
}

// ---------------- GEMM ----------------------------------------------------
__device__ inline void load16_lds(const char* g, char* l) {
  __builtin_amdgcn_global_load_lds(
      (const __attribute__((address_space(1))) void*)g,
      (__attribute__((address_space(3))) void*)l, 16, 0, 0);
}

// reference fp16 cast, saturating (all values >= 0; |inf-finite|=inf passes)
__device__ inline float f16_sat(float v) {
  v = fminf(v, 65504.0f);
  return (float)(_Float16)v;
}

__global__ __launch_bounds__(512, 2) void gemm_i8w8(
    const char* __restrict__ A, const char* __restrict__ B,
    const float* __restrict__ arow, const float* __restrict__ acol,
    float* __restrict__ out) {
  __shared__ char sA[2][TB];  // 64 KiB
  __shared__ char sB[2][TB];  // 64 KiB

  const int tid = threadIdx.x;
  const int wv = tid >> 6;
  const int lane = tid & 63;

  // XCD-aware bijective swizzle (nwg = 256, divisible by 8)
  const int bid = blockIdx.x;
  const int wg = (bid & 7) * 32 + (bid >> 3);
  const int brow = wg >> 4;
  const int bcol = wg & 15;

  // 2(M) x 4(N) wave grid; per-wave output 128 x 64 (4x2 tiles of 32x32)
  const int wrow = (wv >> 2) * 128;
  const int wcol = (wv & 3) * 64;

  i32x16 acc[4][2] = {};

  // ---- staging (verified R4/R5 geometry): one gload_lds stmt = 8 rows x
  // 128B per wave (64 rows x 128B block-wide). LDS dest linear
  // (lane l -> row +(l>>3), slot l&7); source slot pre-swizzled
  // (l&7)^(l>>3), so LDS[row][s] = G[row][s ^ (row&7)] (involution).
  const int lr = lane >> 3, ls = lane & 7;
  const char* aStage = A + (size_t)(brow * BM + wv * 8 + lr) * KD + (ls ^ lr) * 16;
  const char* bStage = B + (size_t)(bcol * BN + wv * 8 + lr) * KD + (ls ^ lr) * 16;
  const int ldsSB = wv * 1024;  // wave's stripe within each 64-row chunk

  auto STAGE = [&](char* dA, char* dB, size_t kb) {  // 8 block-wide loads
#pragma unroll
    for (int s = 0; s < 4; ++s)
      load16_lds(aStage + (size_t)s * 64 * KD + kb, dA + s * 8192 + ldsSB);
#pragma unroll
    for (int s = 0; s < 4; ++s)
      load16_lds(bStage + (size_t)s * 64 * KD + kb, dB + s * 8192 + ldsSB);
  };

  // ---- fragment reads (32x32x32): lane l -> row base + (l&31),
  // G-slot = ks*2 + (l>>5); LDS slot = G-slot ^ (row&7), row&7 = l&7.
  const int l31 = lane & 31, hi = lane >> 5;
  int xs[4];
#pragma unroll
  for (int ks = 0; ks < 4; ++ks) xs[ks] = ((ks * 2 + hi) ^ (lane & 7)) * 16;
  const int aRow = (wrow + l31) * BKB;  // + mt*4096
  const int bRow = (wcol + l31) * BKB;  // + nt*4096

  i32x4 afU[4], afV[4], bfU[2], bfV[2];

  auto rdA = [&](i32x4(&af)[4], const char* p, int ks) {
#pragma unroll
    for (int mt = 0; mt < 4; ++mt)
      af[mt] = *(const i32x4*)(p + aRow + mt * 4096 + xs[ks]);
  };
  auto rdB = [&](i32x4(&bf)[2], const char* p, int ks) {
#pragma unroll
    for (int nt = 0; nt < 2; ++nt)
      bf[nt] = *(const i32x4*)(p + bRow + nt * 4096 + xs[ks]);
  };
  auto cluster = [&](i32x4(&af)[4], i32x4(&bf)[2]) {  // 8 indep acc chains
    __builtin_amdgcn_s_setprio(1);
#pragma unroll
    for (int mt = 0; mt < 4; ++mt)
#pragma unroll
      for (int nt = 0; nt < 2; ++nt)
        acc[mt][nt] = __builtin_amdgcn_mfma_i32_32x32x32_i8(af[mt], bf[nt],
                                                            acc[mt][nt], 0, 0, 0);
    __builtin_amdgcn_s_setprio(0);
  };

  // ---- one K-tile: 4 ks-phases, ONE vmcnt(0)+BAR at P2-end.
  // Safety: stage (P0, buf nb) vs reads of nb ended at P2(i-1) before its
  // barrier; P3 reads nb after this tile's barrier; drain has >=2 phases
  // of slack. Waves may drift between barriers -> LDS/MFMA pipes overlap.
  auto tile_body = [&](const char* pa, const char* pb, char* pan, char* pbn,
                       int i) {
    const bool more = (i + 1) < NT;
    const size_t kb = (size_t)(i + 1) * BKB;
    // P0: MFMA ks0 (U); read ks1 -> V; stage next tile (8 loads)
    rdA(afV, pa, 1);
    rdB(bfV, pb, 1);
    if (more) STAGE(pan, pbn, kb);
    cluster(afU, bfU);
    SCHED_FENCE();
    // P1: MFMA ks1 (V); read ks2 -> U
    rdA(afU, pa, 2);
    rdB(bfU, pb, 2);
    cluster(afV, bfV);
    SCHED_FENCE();
    // P2: MFMA ks2 (U); read ks3 -> V; drain + publish
    rdA(afV, pa, 3);
    rdB(bfV, pb, 3);
    cluster(afU, bfU);
    VMCNT(0);
    BAR();
    SCHED_FENCE();
    // P3: MFMA ks3 (V); read next-tile ks0 -> U
    if (more) {
      rdA(afU, pan, 0);
      rdB(bfU, pbn, 0);
    }
    cluster(afV, bfV);
    SCHED_FENCE();
  };

  // ---- prologue: stage tile 0, drain, publish, read ks0
  STAGE(sA[0], sB[0], 0);
  VMCNT(0);
  BAR();
  rdA(afU, sA[0], 0);
  rdB(bfU, sB[0], 0);

  for (int i = 0; i < NT; i += 2) {  // static buffer parity
    tile_body(sA[0], sB[0], sA[1], sB[1], i);
    tile_body(sA[1], sB[1], sA[0], sB[0], i + 1);
  }

  // ---- epilogue: 32x32 C/D map: col = lane&31,
  // row = (reg&3) + 8*(reg>>2) + 4*(lane>>5)
  const int orow = brow * BM + wrow;
  const int ocol = bcol * BN + wcol + l31;
#pragma unroll
  for (int mt = 0; mt < 4; ++mt) {
#pragma unroll
    for (int nt = 0; nt < 2; ++nt) {
      const int col = ocol + nt * 32;
      const float ac = acol[col];
#pragma unroll
      for (int g = 0; g < 4; ++g) {
        const int r0 = orow + mt * 32 + g * 8 + hi * 4;
        const float4 ar4 = *(const float4*)(arow + r0);
        const float ar[4] = {ar4.x, ar4.y, ar4.z, ar4.w};
#pragma unroll
        for (int j = 0; j < 4; ++j)
          out[(size_t)(r0 + j) * ND + col] =
              f16_sat((float)acc[mt][nt][g * 4 + j] * (ar[j] * ac));
      }
    }
  }
}

extern "C" void kernel_launch(void* const* d_in, const int* in_sizes, int n_in,
                              void* d_out, int out_size, void* d_ws, size_t ws_size,
                              hipStream_t stream) {
  const int* a = (const int*)d_in[0];         // [M,K] int32 (int8 values)
  const int* b = (const int*)d_in[1];         // [N,K] int32 (int8 values)
  const float* arow = (const float*)d_in[2];  // [M,1]
  const float* acol = (const float*)d_in[3];  // [1,N]
  float* out = (float*)d_out;

  char* pa = (char*)d_ws;                    // 16 MiB packed A
  char* pb = pa + (size_t)MD * KD;           // 16 MiB packed B

  const int packBlocks = (int)(((size_t)MD * KD) / (16 * 256));  // 4096
  pack_i8<<<packBlocks, 256, 0, stream>>>(a, pa);
  pack_i8<<<packBlocks, 256, 0, stream>>>(b, pb);

  const int grid = (MD / BM) * (ND / BN);  // 256 blocks, 1 per CU
  gemm_i8w8<<<grid, 512, 0, stream>>>(pa, pb, arow, acol, out);
}